// Round 1
// baseline (2661.735 us; speedup 1.0000x reference)
//
#include <hip/hip_runtime.h>
#include <math.h>

// InvGraphConv: SplineCNN block on MI355X.
// N=20000, E=320000, D=3, KS=5 -> K=125, S=8, Fin=Fout=32, hidden=64.

__device__ __forceinline__ void spline8(const float u0, const float u1, const float u2,
                                        float* __restrict__ b, int* __restrict__ id) {
    const float u[3] = {u0, u1, u2};
    const int strides[3] = {25, 5, 1};
    float fr[3];
    int   i0[3];
#pragma unroll
    for (int d = 0; d < 3; ++d) {
        float p = u[d] * 4.0f;
        float f = floorf(p);
        f = fminf(fmaxf(f, 0.0f), 3.0f);
        i0[d] = (int)f;
        fr[d] = p - f;
    }
#pragma unroll
    for (int s = 0; s < 8; ++s) {
        float bb = 1.0f;
        int   ii = 0;
#pragma unroll
        for (int d = 0; d < 3; ++d) {
            int c = (s >> d) & 1;
            bb *= c ? fr[d] : (1.0f - fr[d]);
            ii += (i0[d] + c) * strides[d];
        }
        b[s] = bb;
        id[s] = ii;
    }
}

__global__ void deg_kernel(const int* __restrict__ row, float* __restrict__ deg, int E) {
    int e = blockIdx.x * blockDim.x + threadIdx.x;
    if (e < E) atomicAdd(&deg[row[e]], 1.0f);
}

__global__ void basis1_kernel(const float* __restrict__ pseudo,
                              float* __restrict__ basis, int* __restrict__ idx, int E) {
    int e = blockIdx.x * blockDim.x + threadIdx.x;
    if (e >= E) return;
    float b[8]; int id[8];
    spline8(pseudo[e * 3 + 0], pseudo[e * 3 + 1], pseudo[e * 3 + 2], b, id);
#pragma unroll
    for (int s = 0; s < 8; ++s) { basis[e * 8 + s] = b[s]; idx[e * 8 + s] = id[s]; }
}

__global__ void basis2_kernel(const float* __restrict__ pseudo, const float* __restrict__ t,
                              const int* __restrict__ row, const int* __restrict__ col,
                              float* __restrict__ basis, int* __restrict__ idx, int E) {
    int e = blockIdx.x * blockDim.x + threadIdx.x;
    if (e >= E) return;
    int r = row[e], c = col[e];
    float u[3];
#pragma unroll
    for (int d = 0; d < 3; ++d) {
        float v = pseudo[e * 3 + d] + t[c * 3 + d] - t[r * 3 + d];
        u[d] = fminf(fmaxf(v, 0.0f), 1.0f);
    }
    float b[8]; int id[8];
    spline8(u[0], u[1], u[2], b, id);
#pragma unroll
    for (int s = 0; s < 8; ++s) { basis[e * 8 + s] = b[s]; idx[e * 8 + s] = id[s]; }
}

// conv1: x == ones[N,1], W1 [125,1,64] -> msg[e,o] = sum_s b_s * W1[idx_s, 0, o]
__global__ void conv1_kernel(const float* __restrict__ basis, const int* __restrict__ idx,
                             const int* __restrict__ row, const float* __restrict__ W1,
                             float* __restrict__ acc, int E) {
    int t = blockIdx.x * blockDim.x + threadIdx.x;
    if (t >= E * 64) return;
    int e = t >> 6, o = t & 63;
    float m = 0.0f;
#pragma unroll
    for (int s = 0; s < 8; ++s) {
        m += basis[e * 8 + s] * W1[idx[e * 8 + s] * 64 + o];
    }
    atomicAdd(&acc[row[e] * 64 + o], m);
}

// finalize: h = (elu?)(acc/max(deg,1) + bias)
__global__ void finalize_kernel(const float* __restrict__ acc, const float* __restrict__ deg,
                                const float* __restrict__ bias, float* __restrict__ h,
                                int N, int F, int do_elu) {
    int t = blockIdx.x * blockDim.x + threadIdx.x;
    if (t >= N * F) return;
    int n = t / F, o = t % F;
    float v = acc[t] / fmaxf(deg[n], 1.0f) + bias[o];
    if (do_elu) v = (v > 0.0f) ? v : (expf(v) - 1.0f);
    h[t] = v;
}

// conv2: wave per edge, lane = output channel (64). h1[col] staged in LDS.
__global__ __launch_bounds__(256) void conv2_kernel(
        const float* __restrict__ h1, const float* __restrict__ basis,
        const int* __restrict__ idx, const int* __restrict__ row,
        const int* __restrict__ col, const float* __restrict__ W2,
        float* __restrict__ acc, int E) {
    int wid = threadIdx.x >> 6;
    int lane = threadIdx.x & 63;
    int e = blockIdx.x * 4 + wid;
    __shared__ float sh[4][64];
    bool active = (e < E);
    int c = active ? col[e] : 0;
    if (active) sh[wid][lane] = h1[c * 64 + lane];
    __syncthreads();
    if (!active) return;
    float b[8]; int id[8];
#pragma unroll
    for (int s = 0; s < 8; ++s) { b[s] = basis[e * 8 + s]; id[s] = idx[e * 8 + s]; }
    float m = 0.0f;
#pragma unroll
    for (int s = 0; s < 8; ++s) {
        const float* Wk = W2 + (size_t)id[s] * 4096;
        float ms = 0.0f;
#pragma unroll
        for (int i = 0; i < 64; ++i) ms += sh[wid][i] * Wk[i * 64 + lane];
        m += b[s] * ms;
    }
    atomicAdd(&acc[row[e] * 64 + lane], m);
}

// stn3 + stn4 per node: h3 = elu(h2 @ w3 + b3); t = h3 @ w4 + b4
__global__ __launch_bounds__(64) void stn34_kernel(
        const float* __restrict__ h2, const float* __restrict__ w3,
        const float* __restrict__ b3, const float* __restrict__ w4,
        const float* __restrict__ b4, float* __restrict__ t, int N) {
    int n = blockIdx.x;
    int o = threadIdx.x;
    __shared__ float sh[64];
    __shared__ float sh3[64];
    sh[o] = h2[n * 64 + o];
    __syncthreads();
    float v = b3[o];
#pragma unroll
    for (int i = 0; i < 64; ++i) v += sh[i] * w3[i * 64 + o];
    v = (v > 0.0f) ? v : (expf(v) - 1.0f);
    sh3[o] = v;
    __syncthreads();
    if (o < 3) {
        float tv = b4[o];
#pragma unroll
        for (int i = 0; i < 64; ++i) tv += sh3[i] * w4[i * 3 + o];
        t[n * 3 + o] = tv;
    }
}

// conv3: wave per edge; lanes split: half = lane>>5 handles s in {0..3} or {4..7},
// o = lane&31. Partial sums combined via shfl_xor(32), lanes<32 do the atomic.
__global__ __launch_bounds__(256) void conv3_kernel(
        const float* __restrict__ x, const float* __restrict__ basis,
        const int* __restrict__ idx, const int* __restrict__ row,
        const int* __restrict__ col, const float* __restrict__ Wc,
        float* __restrict__ acc, int E) {
    int wid = threadIdx.x >> 6;
    int lane = threadIdx.x & 63;
    int e = blockIdx.x * 4 + wid;
    __shared__ float sx[4][32];
    bool active = (e < E);
    int c = active ? col[e] : 0;
    if (active && lane < 32) sx[wid][lane] = x[c * 32 + lane];
    __syncthreads();
    int half = lane >> 5;
    int o = lane & 31;
    float m = 0.0f;
    if (active) {
#pragma unroll
        for (int s2 = 0; s2 < 4; ++s2) {
            int s = half * 4 + s2;
            float b = basis[e * 8 + s];
            const float* Wk = Wc + (size_t)idx[e * 8 + s] * 1024;
            float ms = 0.0f;
#pragma unroll
            for (int i = 0; i < 32; ++i) ms += sx[wid][i] * Wk[i * 32 + o];
            m += b * ms;
        }
    }
    m += __shfl_xor(m, 32);
    if (active && lane < 32) atomicAdd(&acc[row[e] * 32 + o], m);
}

extern "C" void kernel_launch(void* const* d_in, const int* in_sizes, int n_in,
                              void* d_out, int out_size, void* d_ws, size_t ws_size,
                              hipStream_t stream) {
    const float* x      = (const float*)d_in[0];
    const int*   ei     = (const int*)d_in[1];
    const float* pseudo = (const float*)d_in[2];
    const float* w1     = (const float*)d_in[3];
    const float* b1     = (const float*)d_in[4];
    const float* w2     = (const float*)d_in[5];
    const float* b2     = (const float*)d_in[6];
    const float* w3     = (const float*)d_in[7];
    const float* b3     = (const float*)d_in[8];
    const float* w4     = (const float*)d_in[9];
    const float* b4     = (const float*)d_in[10];
    const float* wc     = (const float*)d_in[11];
    const float* cb     = (const float*)d_in[12];
    float* out = (float*)d_out;

    const int N = in_sizes[0] / 32;
    const int E = in_sizes[1] / 2;
    const int* row = ei;
    const int* col = ei + E;

    char* p = (char*)d_ws;
    float* deg  = (float*)p; p += (size_t)N * sizeof(float);
    float* acc1 = (float*)p; p += (size_t)N * 64 * sizeof(float);
    float* acc2 = (float*)p; p += (size_t)N * 64 * sizeof(float);
    float* acc3 = (float*)p; p += (size_t)N * 32 * sizeof(float);
    size_t zero_bytes = (size_t)(p - (char*)d_ws);
    float* h1   = (float*)p; p += (size_t)N * 64 * sizeof(float);
    float* h2   = (float*)p; p += (size_t)N * 64 * sizeof(float);
    float* tt   = (float*)p; p += (size_t)N * 3 * sizeof(float);
    float* basis = (float*)p; p += (size_t)E * 8 * sizeof(float);
    int*   idx   = (int*)p;  p += (size_t)E * 8 * sizeof(int);

    hipMemsetAsync(d_ws, 0, zero_bytes, stream);

    deg_kernel<<<(E + 255) / 256, 256, 0, stream>>>(row, deg, E);
    basis1_kernel<<<(E + 255) / 256, 256, 0, stream>>>(pseudo, basis, idx, E);
    conv1_kernel<<<((size_t)E * 64 + 255) / 256, 256, 0, stream>>>(basis, idx, row, w1, acc1, E);
    finalize_kernel<<<(N * 64 + 255) / 256, 256, 0, stream>>>(acc1, deg, b1, h1, N, 64, 1);
    conv2_kernel<<<(E + 3) / 4, 256, 0, stream>>>(h1, basis, idx, row, col, w2, acc2, E);
    finalize_kernel<<<(N * 64 + 255) / 256, 256, 0, stream>>>(acc2, deg, b2, h2, N, 64, 1);
    stn34_kernel<<<N, 64, 0, stream>>>(h2, w3, b3, w4, b4, tt, N);
    basis2_kernel<<<(E + 255) / 256, 256, 0, stream>>>(pseudo, tt, row, col, basis, idx, E);
    conv3_kernel<<<(E + 3) / 4, 256, 0, stream>>>(x, basis, idx, row, col, wc, acc3, E);
    finalize_kernel<<<(N * 32 + 255) / 256, 256, 0, stream>>>(acc3, deg, cb, out, N, 32, 0);
}

// Round 2
// 933.267 us; speedup vs baseline: 2.8521x; 2.8521x over previous
//
#include <hip/hip_runtime.h>
#include <hip/hip_bf16.h>
#include <math.h>

// InvGraphConv: SplineCNN block on MI355X.
// N=20000, E=320000, D=3, KS=5 -> K=125, S=8, Fin=Fout=32, hidden=64.
//
// R2: conv2/conv3 restructured as z-precompute GEMM (bf16 MFMA) + edge gather.
//   z2[n, k*64+o] = sum_i h1[n,i] * W2[k,i,o]   (bf16 out, 320MB)
//   z3[n, k*32+o] = sum_i x[n,i]  * Wc[k,i,o]   (f32 out, 320MB)
// then msg[e,o] = sum_s basis[e,s] * z[col[e], idx[e,s], o], atomically
// scattered to acc[row[e]]. Host chunks over k if ws is small.

typedef short  s16x8 __attribute__((ext_vector_type(8)));
typedef float  f32x4 __attribute__((ext_vector_type(4)));

__device__ __forceinline__ unsigned short f2b(float f) {
    __hip_bfloat16 h = __float2bfloat16(f);
    return __builtin_bit_cast(unsigned short, h);
}
__device__ __forceinline__ float b2f(unsigned short u) {
    __hip_bfloat16 h = __builtin_bit_cast(__hip_bfloat16, u);
    return __bfloat162float(h);
}

__device__ __forceinline__ void spline8(const float u0, const float u1, const float u2,
                                        float* __restrict__ b, int* __restrict__ id) {
    const float u[3] = {u0, u1, u2};
    const int strides[3] = {25, 5, 1};
    float fr[3];
    int   i0[3];
#pragma unroll
    for (int d = 0; d < 3; ++d) {
        float p = u[d] * 4.0f;
        float f = floorf(p);
        f = fminf(fmaxf(f, 0.0f), 3.0f);
        i0[d] = (int)f;
        fr[d] = p - f;
    }
#pragma unroll
    for (int s = 0; s < 8; ++s) {
        float bb = 1.0f;
        int   ii = 0;
#pragma unroll
        for (int d = 0; d < 3; ++d) {
            int c = (s >> d) & 1;
            bb *= c ? fr[d] : (1.0f - fr[d]);
            ii += (i0[d] + c) * strides[d];
        }
        b[s] = bb;
        id[s] = ii;
    }
}

__global__ void deg_kernel(const int* __restrict__ row, float* __restrict__ deg, int E) {
    int e = blockIdx.x * blockDim.x + threadIdx.x;
    if (e < E) atomicAdd(&deg[row[e]], 1.0f);
}

__global__ void basis1_kernel(const float* __restrict__ pseudo,
                              float* __restrict__ basis, int* __restrict__ idx, int E) {
    int e = blockIdx.x * blockDim.x + threadIdx.x;
    if (e >= E) return;
    float b[8]; int id[8];
    spline8(pseudo[e * 3 + 0], pseudo[e * 3 + 1], pseudo[e * 3 + 2], b, id);
#pragma unroll
    for (int s = 0; s < 8; ++s) { basis[e * 8 + s] = b[s]; idx[e * 8 + s] = id[s]; }
}

__global__ void basis2_kernel(const float* __restrict__ pseudo, const float* __restrict__ t,
                              const int* __restrict__ row, const int* __restrict__ col,
                              float* __restrict__ basis, int* __restrict__ idx, int E) {
    int e = blockIdx.x * blockDim.x + threadIdx.x;
    if (e >= E) return;
    int r = row[e], c = col[e];
    float u[3];
#pragma unroll
    for (int d = 0; d < 3; ++d) {
        float v = pseudo[e * 3 + d] + t[c * 3 + d] - t[r * 3 + d];
        u[d] = fminf(fmaxf(v, 0.0f), 1.0f);
    }
    float b[8]; int id[8];
    spline8(u[0], u[1], u[2], b, id);
#pragma unroll
    for (int s = 0; s < 8; ++s) { basis[e * 8 + s] = b[s]; idx[e * 8 + s] = id[s]; }
}

// conv1: h==ones -> msg[e,o] = sum_s b_s * W1[idx_s, 0, o]
__global__ void conv1_kernel(const float* __restrict__ basis, const int* __restrict__ idx,
                             const int* __restrict__ row, const float* __restrict__ W1,
                             float* __restrict__ acc, int E) {
    int t = blockIdx.x * blockDim.x + threadIdx.x;
    if (t >= E * 64) return;
    int e = t >> 6, o = t & 63;
    float m = 0.0f;
#pragma unroll
    for (int s = 0; s < 8; ++s) {
        m += basis[e * 8 + s] * W1[idx[e * 8 + s] * 64 + o];
    }
    atomicAdd(&acc[row[e] * 64 + o], m);
}

// h = (elu?)(acc/max(deg,1) + bias); optional fp32 and/or bf16 outputs
__global__ void finalize_kernel(const float* __restrict__ acc, const float* __restrict__ deg,
                                const float* __restrict__ bias, float* __restrict__ outF,
                                unsigned short* __restrict__ outB,
                                int N, int F, int do_elu) {
    int t = blockIdx.x * blockDim.x + threadIdx.x;
    if (t >= N * F) return;
    int n = t / F, o = t % F;
    float v = acc[t] / fmaxf(deg[n], 1.0f) + bias[o];
    if (do_elu) v = (v > 0.0f) ? v : (expf(v) - 1.0f);
    if (outF) outF[t] = v;
    if (outB) outB[t] = f2b(v);
}

// generic fp32 -> bf16 cast
__global__ void castbf_kernel(const float* __restrict__ in, unsigned short* __restrict__ out,
                              int n) {
    int t = blockIdx.x * blockDim.x + threadIdx.x;
    if (t < n) out[t] = f2b(in[t]);
}

// Pack W [Kc][Fin][Fout] (fp32) into MFMA B-fragment order (bf16):
// value B[i][c] with c = kk*Fout+o; fragment addr
//   ((((ct*ksteps + step)*4 + lg)*16 + lr)*8 + j
// where ct=c>>4, lr=c&15, i = step*32 + lg*8 + j.
__global__ void pack_w_kernel(const float* __restrict__ W, unsigned short* __restrict__ BF,
                              int Kc, int Fin, int Fout, int ksteps) {
    int t = blockIdx.x * blockDim.x + threadIdx.x;
    int total = Kc * Fout * Fin;
    if (t >= total) return;
    int c = t / Fin;
    int i = t % Fin;
    int kk = c / Fout, o = c % Fout;
    int ct = c >> 4, lr = c & 15;
    int step = i >> 5, rem = i & 31, lg = rem >> 3, j = rem & 7;
    size_t dst = ((((size_t)ct * ksteps + step) * 4 + lg) * 16 + lr) * 8 + j;
    BF[dst] = f2b(W[((size_t)kk * Fin + i) * Fout + o]);
}

// z = A @ B via mfma_f32_16x16x32_bf16. A [M][KSTEPS*32] bf16 row-major.
// BF fragment-packed (see pack_w_kernel). Block = 4 waves, each wave does a
// 16-row x 64-col tile (4 col-frags). Z chunk is [M][zld], col-tile ct0 offset.
template<int KSTEPS, int OUT_BF16>
__global__ __launch_bounds__(256) void zgemm_kernel(
        const unsigned short* __restrict__ A, int M,
        const unsigned short* __restrict__ BF,
        void* __restrict__ Z, int zld, int ct0, int zct) {
    int w = threadIdx.x >> 6, l = threadIdx.x & 63;
    int m0 = blockIdx.x * 64 + w * 16;
    int lr = l & 15, lg = l >> 4;
    const int KD = KSTEPS * 32;
    f32x4 acc[4];
#pragma unroll
    for (int cf = 0; cf < 4; ++cf) acc[cf] = (f32x4){0.f, 0.f, 0.f, 0.f};
    int arow = m0 + lr; if (arow > M - 1) arow = M - 1;
#pragma unroll
    for (int step = 0; step < KSTEPS; ++step) {
        s16x8 a = *(const s16x8*)(A + (size_t)arow * KD + step * 32 + lg * 8);
#pragma unroll
        for (int cf = 0; cf < 4; ++cf) {
            int ctl = blockIdx.y * 4 + cf;
            if (ctl < zct) {
                int ctg = ct0 + ctl;
                const unsigned short* bp =
                    BF + ((((size_t)ctg * KSTEPS + step) * 4 + lg) * 16 + lr) * 8;
                s16x8 b = *(const s16x8*)bp;
                acc[cf] = __builtin_amdgcn_mfma_f32_16x16x32_bf16(a, b, acc[cf], 0, 0, 0);
            }
        }
    }
#pragma unroll
    for (int cf = 0; cf < 4; ++cf) {
        int ctl = blockIdx.y * 4 + cf;
        if (ctl >= zct) continue;
        int colc = ctl * 16 + lr;
#pragma unroll
        for (int r = 0; r < 4; ++r) {
            int rowc = m0 + lg * 4 + r;
            if (rowc < M) {
                if (OUT_BF16)
                    ((unsigned short*)Z)[(size_t)rowc * zld + colc] = f2b(acc[cf][r]);
                else
                    ((float*)Z)[(size_t)rowc * zld + colc] = acc[cf][r];
            }
        }
    }
}

// gather conv2: wave per edge, lane = out channel (64). z bf16 [N][zld].
__global__ __launch_bounds__(256) void gather2_kernel(
        const unsigned short* __restrict__ z, int zld,
        const float* __restrict__ basis, const int* __restrict__ idx,
        const int* __restrict__ row, const int* __restrict__ col,
        float* __restrict__ acc, int E, int k0, int k1) {
    int w = threadIdx.x >> 6, l = threadIdx.x & 63;
    int e = blockIdx.x * 4 + w;
    if (e >= E) return;
    size_t zbase = (size_t)col[e] * zld;
    float m = 0.0f;
    bool any = false;
#pragma unroll
    for (int s = 0; s < 8; ++s) {
        int k = idx[e * 8 + s];
        if (k >= k0 && k < k1) {
            m += basis[e * 8 + s] * b2f(z[zbase + (size_t)(k - k0) * 64 + l]);
            any = true;
        }
    }
    if (any) atomicAdd(&acc[(size_t)row[e] * 64 + l], m);
}

// gather conv3: 32 lanes per edge. z3 fp32 [N][zld].
__global__ __launch_bounds__(256) void gather3_kernel(
        const float* __restrict__ z, int zld,
        const float* __restrict__ basis, const int* __restrict__ idx,
        const int* __restrict__ row, const int* __restrict__ col,
        float* __restrict__ acc, int E, int k0, int k1) {
    int t = blockIdx.x * blockDim.x + threadIdx.x;
    int e = t >> 5, o = t & 31;
    if (e >= E) return;
    size_t zbase = (size_t)col[e] * zld;
    float m = 0.0f;
    bool any = false;
#pragma unroll
    for (int s = 0; s < 8; ++s) {
        int k = idx[e * 8 + s];
        if (k >= k0 && k < k1) {
            m += basis[e * 8 + s] * z[zbase + (size_t)(k - k0) * 32 + o];
            any = true;
        }
    }
    if (any) atomicAdd(&acc[(size_t)row[e] * 32 + o], m);
}

// stn3 + stn4 per node: h3 = elu(h2 @ w3 + b3); t = h3 @ w4 + b4
__global__ __launch_bounds__(64) void stn34_kernel(
        const float* __restrict__ h2, const float* __restrict__ w3,
        const float* __restrict__ b3, const float* __restrict__ w4,
        const float* __restrict__ b4, float* __restrict__ t, int N) {
    int n = blockIdx.x;
    int o = threadIdx.x;
    __shared__ float sh[64];
    __shared__ float sh3[64];
    sh[o] = h2[n * 64 + o];
    __syncthreads();
    float v = b3[o];
#pragma unroll
    for (int i = 0; i < 64; ++i) v += sh[i] * w3[i * 64 + o];
    v = (v > 0.0f) ? v : (expf(v) - 1.0f);
    sh3[o] = v;
    __syncthreads();
    if (o < 3) {
        float tv = b4[o];
#pragma unroll
        for (int i = 0; i < 64; ++i) tv += sh3[i] * w4[i * 3 + o];
        t[n * 3 + o] = tv;
    }
}

// ---- fallback (R1) kernels, used only if ws too small ----
__global__ __launch_bounds__(256) void conv2_kernel(
        const float* __restrict__ h1, const float* __restrict__ basis,
        const int* __restrict__ idx, const int* __restrict__ row,
        const int* __restrict__ col, const float* __restrict__ W2,
        float* __restrict__ acc, int E) {
    int wid = threadIdx.x >> 6;
    int lane = threadIdx.x & 63;
    int e = blockIdx.x * 4 + wid;
    __shared__ float sh[4][64];
    bool active = (e < E);
    int c = active ? col[e] : 0;
    if (active) sh[wid][lane] = h1[c * 64 + lane];
    __syncthreads();
    if (!active) return;
    float b[8]; int id[8];
#pragma unroll
    for (int s = 0; s < 8; ++s) { b[s] = basis[e * 8 + s]; id[s] = idx[e * 8 + s]; }
    float m = 0.0f;
#pragma unroll
    for (int s = 0; s < 8; ++s) {
        const float* Wk = W2 + (size_t)id[s] * 4096;
        float ms = 0.0f;
#pragma unroll
        for (int i = 0; i < 64; ++i) ms += sh[wid][i] * Wk[i * 64 + lane];
        m += b[s] * ms;
    }
    atomicAdd(&acc[row[e] * 64 + lane], m);
}

__global__ __launch_bounds__(256) void conv3_kernel(
        const float* __restrict__ x, const float* __restrict__ basis,
        const int* __restrict__ idx, const int* __restrict__ row,
        const int* __restrict__ col, const float* __restrict__ Wc,
        float* __restrict__ acc, int E) {
    int wid = threadIdx.x >> 6;
    int lane = threadIdx.x & 63;
    int e = blockIdx.x * 4 + wid;
    __shared__ float sx[4][32];
    bool active = (e < E);
    int c = active ? col[e] : 0;
    if (active && lane < 32) sx[wid][lane] = x[c * 32 + lane];
    __syncthreads();
    int half = lane >> 5;
    int o = lane & 31;
    float m = 0.0f;
    if (active) {
#pragma unroll
        for (int s2 = 0; s2 < 4; ++s2) {
            int s = half * 4 + s2;
            float b = basis[e * 8 + s];
            const float* Wk = Wc + (size_t)idx[e * 8 + s] * 1024;
            float ms = 0.0f;
#pragma unroll
            for (int i = 0; i < 32; ++i) ms += sx[wid][i] * Wk[i * 32 + o];
            m += b * ms;
        }
    }
    m += __shfl_xor(m, 32);
    if (active && lane < 32) atomicAdd(&acc[row[e] * 32 + o], m);
}

extern "C" void kernel_launch(void* const* d_in, const int* in_sizes, int n_in,
                              void* d_out, int out_size, void* d_ws, size_t ws_size,
                              hipStream_t stream) {
    const float* x      = (const float*)d_in[0];
    const int*   ei     = (const int*)d_in[1];
    const float* pseudo = (const float*)d_in[2];
    const float* w1     = (const float*)d_in[3];
    const float* b1     = (const float*)d_in[4];
    const float* w2     = (const float*)d_in[5];
    const float* b2     = (const float*)d_in[6];
    const float* w3     = (const float*)d_in[7];
    const float* b3     = (const float*)d_in[8];
    const float* w4     = (const float*)d_in[9];
    const float* b4     = (const float*)d_in[10];
    const float* wc     = (const float*)d_in[11];
    const float* cb     = (const float*)d_in[12];
    float* out = (float*)d_out;

    const int N = in_sizes[0] / 32;
    const int E = in_sizes[1] / 2;
    const int* row = ei;
    const int* col = ei + E;
    const int KC = 125;

    char* p = (char*)d_ws;
    // zeroed region
    float* deg  = (float*)p; p += (size_t)N * sizeof(float);
    float* acc1 = (float*)p; p += (size_t)N * 64 * sizeof(float);
    float* acc2 = (float*)p; p += (size_t)N * 64 * sizeof(float);
    float* acc3 = (float*)p; p += (size_t)N * 32 * sizeof(float);
    size_t zero_bytes = (size_t)(p - (char*)d_ws);
    // non-zeroed
    float* h2   = (float*)p; p += (size_t)N * 64 * sizeof(float);
    float* tt   = (float*)p; p += (size_t)N * 3 * sizeof(float);
    float* basis = (float*)p; p += (size_t)E * 8 * sizeof(float);
    int*   idx   = (int*)p;  p += (size_t)E * 8 * sizeof(int);
    unsigned short* h1b = (unsigned short*)p; p += (size_t)N * 64 * sizeof(short);
    unsigned short* xb  = (unsigned short*)p; p += (size_t)N * 32 * sizeof(short);
    unsigned short* BF2 = (unsigned short*)p; p += (size_t)KC * 64 * 64 * sizeof(short);
    unsigned short* BF3 = (unsigned short*)p; p += (size_t)KC * 32 * 32 * sizeof(short);
    // fallback path needs h1 fp32
    float* h1f = (float*)p; // overlaps z area; only used in fallback
    size_t fixed = (size_t)(p - (char*)d_ws);
    size_t zcap = (ws_size > fixed) ? (ws_size - fixed) : 0;

    const size_t z2_per_k = (size_t)N * 64 * sizeof(short);   // bf16
    const size_t z3_per_k = (size_t)N * 32 * sizeof(float);   // fp32
    int KC2 = (int)(zcap / z2_per_k); if (KC2 > KC) KC2 = KC;
    int KC3 = (int)(zcap / z3_per_k); if (KC3 > KC) KC3 = KC;
    bool fast2 = KC2 >= 1;
    bool fast3 = KC3 >= 1;
    void* zbuf = (void*)p;

    hipMemsetAsync(d_ws, 0, zero_bytes, stream);

    // prep (graph-independent)
    if (fast2)
        pack_w_kernel<<<(KC * 64 * 64 + 255) / 256, 256, 0, stream>>>(w2, BF2, KC, 64, 64, 2);
    if (fast3) {
        pack_w_kernel<<<(KC * 32 * 32 + 255) / 256, 256, 0, stream>>>(wc, BF3, KC, 32, 32, 1);
        castbf_kernel<<<(N * 32 + 255) / 256, 256, 0, stream>>>(x, xb, N * 32);
    }

    deg_kernel<<<(E + 255) / 256, 256, 0, stream>>>(row, deg, E);
    basis1_kernel<<<(E + 255) / 256, 256, 0, stream>>>(pseudo, basis, idx, E);
    conv1_kernel<<<((size_t)E * 64 + 255) / 256, 256, 0, stream>>>(basis, idx, row, w1, acc1, E);
    finalize_kernel<<<(N * 64 + 255) / 256, 256, 0, stream>>>(
        acc1, deg, b1, fast2 ? nullptr : h1f, fast2 ? h1b : nullptr, N, 64, 1);

    const int MT = (N + 63) / 64;  // GEMM row-tiles of 64

    // ---- conv2 ----
    if (fast2) {
        for (int k0 = 0; k0 < KC; k0 += KC2) {
            int kcur = KC - k0 < KC2 ? KC - k0 : KC2;
            int zld = kcur * 64;
            dim3 g(MT, kcur);
            zgemm_kernel<2, 1><<<g, 256, 0, stream>>>(h1b, N, BF2, zbuf, zld,
                                                      k0 * 4, kcur * 4);
            gather2_kernel<<<(E + 3) / 4, 256, 0, stream>>>(
                (const unsigned short*)zbuf, zld, basis, idx, row, col, acc2, E,
                k0, k0 + kcur);
        }
    } else {
        conv2_kernel<<<(E + 3) / 4, 256, 0, stream>>>(h1f, basis, idx, row, col, w2, acc2, E);
    }
    finalize_kernel<<<(N * 64 + 255) / 256, 256, 0, stream>>>(acc2, deg, b2, h2, nullptr, N, 64, 1);

    stn34_kernel<<<N, 64, 0, stream>>>(h2, w3, b3, w4, b4, tt, N);
    basis2_kernel<<<(E + 255) / 256, 256, 0, stream>>>(pseudo, tt, row, col, basis, idx, E);

    // ---- conv3 ----
    if (fast3) {
        for (int k0 = 0; k0 < KC; k0 += KC3) {
            int kcur = KC - k0 < KC3 ? KC - k0 : KC3;
            int zld = kcur * 32;
            dim3 g(MT, (kcur * 32 + 63) / 64);
            zgemm_kernel<1, 0><<<g, 256, 0, stream>>>(xb, N, BF3, zbuf, zld,
                                                      k0 * 2, kcur * 2);
            gather3_kernel<<<((size_t)E * 32 + 255) / 256, 256, 0, stream>>>(
                (const float*)zbuf, zld, basis, idx, row, col, acc3, E, k0, k0 + kcur);
        }
    } else {
        conv3_kernel<<<(E + 3) / 4, 256, 0, stream>>>(x, basis, idx, row, col, wc, acc3, E);
    }
    finalize_kernel<<<(N * 32 + 255) / 256, 256, 0, stream>>>(acc3, deg, cb, out, nullptr, N, 32, 0);
}

// Round 3
// 720.171 us; speedup vs baseline: 3.6960x; 1.2959x over previous
//
#include <hip/hip_runtime.h>
#include <hip/hip_bf16.h>
#include <math.h>

// InvGraphConv: SplineCNN block on MI355X.
// N=20000, E=320000, D=3, KS=5 -> K=125, S=8, Fin=Fout=32, hidden=64.
//
// R3: edges counting-sorted by col so gather reads stream (all edges of a
// col-node read the same 16KB z row); basis/idx written in sorted order;
// XCD-swizzled gather blocks; z3 now bf16.

typedef short  s16x8 __attribute__((ext_vector_type(8)));
typedef float  f32x4 __attribute__((ext_vector_type(4)));

__device__ __forceinline__ unsigned short f2b(float f) {
    __hip_bfloat16 h = __float2bfloat16(f);
    return __builtin_bit_cast(unsigned short, h);
}
__device__ __forceinline__ float b2f(unsigned short u) {
    __hip_bfloat16 h = __builtin_bit_cast(__hip_bfloat16, u);
    return __bfloat162float(h);
}

__device__ __forceinline__ int swzblk() {
    int b = blockIdx.x, n = gridDim.x;
    if ((n & 7) == 0) { int q = n >> 3; b = (b & 7) * q + (b >> 3); }
    return b;
}

__device__ __forceinline__ void spline8(const float u0, const float u1, const float u2,
                                        float* __restrict__ b, int* __restrict__ id) {
    const float u[3] = {u0, u1, u2};
    const int strides[3] = {25, 5, 1};
    float fr[3];
    int   i0[3];
#pragma unroll
    for (int d = 0; d < 3; ++d) {
        float p = u[d] * 4.0f;
        float f = floorf(p);
        f = fminf(fmaxf(f, 0.0f), 3.0f);
        i0[d] = (int)f;
        fr[d] = p - f;
    }
#pragma unroll
    for (int s = 0; s < 8; ++s) {
        float bb = 1.0f;
        int   ii = 0;
#pragma unroll
        for (int d = 0; d < 3; ++d) {
            int c = (s >> d) & 1;
            bb *= c ? fr[d] : (1.0f - fr[d]);
            ii += (i0[d] + c) * strides[d];
        }
        b[s] = bb;
        id[s] = ii;
    }
}

// deg over row (float) + hist over col (int), one pass
__global__ void histdeg_kernel(const int* __restrict__ row, const int* __restrict__ col,
                               float* __restrict__ deg, int* __restrict__ hist, int E) {
    int e = blockIdx.x * blockDim.x + threadIdx.x;
    if (e >= E) return;
    atomicAdd(&deg[row[e]], 1.0f);
    atomicAdd(&hist[col[e]], 1);
}

// single-block exclusive scan of hist[N] -> cursor[N]
__global__ __launch_bounds__(1024) void scan_kernel(const int* __restrict__ hist,
                                                    int* __restrict__ cursor, int N) {
    __shared__ int wsum[16];
    __shared__ int carry;
    int t = threadIdx.x, lane = t & 63, w = t >> 6;
    if (t == 0) carry = 0;
    __syncthreads();
    for (int base = 0; base < N; base += 1024) {
        int i = base + t;
        int v = (i < N) ? hist[i] : 0;
        int sc = v;
#pragma unroll
        for (int off = 1; off < 64; off <<= 1) {
            int u = __shfl_up(sc, off);
            if (lane >= off) sc += u;
        }
        if (lane == 63) wsum[w] = sc;
        __syncthreads();
        if (w == 0 && lane < 16) {
            int s = wsum[lane];
#pragma unroll
            for (int off = 1; off < 16; off <<= 1) {
                int u = __shfl_up(s, off);
                if (lane >= off) s += u;
            }
            wsum[lane] = s;
        }
        __syncthreads();
        int woff = (w > 0 ? wsum[w - 1] : 0) + carry;
        int excl = woff + sc - v;
        if (i < N) cursor[i] = excl;
        __syncthreads();
        if (t == 0) carry += wsum[15];
        __syncthreads();
    }
}

// perm scatter: jpos[e] = sorted slot; rowS/colS in sorted order
__global__ void scatter_kernel(const int* __restrict__ row, const int* __restrict__ col,
                               int* __restrict__ cursor, int* __restrict__ jpos,
                               int* __restrict__ rowS, int* __restrict__ colS, int E) {
    int e = blockIdx.x * blockDim.x + threadIdx.x;
    if (e >= E) return;
    int c = col[e];
    int j = atomicAdd(&cursor[c], 1);
    jpos[e] = j;
    rowS[j] = row[e];
    colS[j] = c;
}

__global__ void basis1_kernel(const float* __restrict__ pseudo, const int* __restrict__ jpos,
                              float* __restrict__ basis, int* __restrict__ idx, int E) {
    int e = blockIdx.x * blockDim.x + threadIdx.x;
    if (e >= E) return;
    float b[8]; int id[8];
    spline8(pseudo[e * 3 + 0], pseudo[e * 3 + 1], pseudo[e * 3 + 2], b, id);
    int j = jpos ? jpos[e] : e;
#pragma unroll
    for (int s = 0; s < 8; ++s) { basis[j * 8 + s] = b[s]; idx[j * 8 + s] = id[s]; }
}

__global__ void basis2_kernel(const float* __restrict__ pseudo, const float* __restrict__ t,
                              const int* __restrict__ row, const int* __restrict__ col,
                              const int* __restrict__ jpos,
                              float* __restrict__ basis, int* __restrict__ idx, int E) {
    int e = blockIdx.x * blockDim.x + threadIdx.x;
    if (e >= E) return;
    int r = row[e], c = col[e];
    float u[3];
#pragma unroll
    for (int d = 0; d < 3; ++d) {
        float v = pseudo[e * 3 + d] + t[c * 3 + d] - t[r * 3 + d];
        u[d] = fminf(fmaxf(v, 0.0f), 1.0f);
    }
    float b[8]; int id[8];
    spline8(u[0], u[1], u[2], b, id);
    int j = jpos ? jpos[e] : e;
#pragma unroll
    for (int s = 0; s < 8; ++s) { basis[j * 8 + s] = b[s]; idx[j * 8 + s] = id[s]; }
}

// conv1 (h==ones): wave per sorted edge, lane = channel.
__global__ __launch_bounds__(256) void conv1_kernel(
        const float* __restrict__ basis, const int* __restrict__ idx,
        const int* __restrict__ rowS, const float* __restrict__ W1,
        float* __restrict__ acc, int E) {
    int b = swzblk();
    int j = b * 4 + (threadIdx.x >> 6);
    if (j >= E) return;
    int l = threadIdx.x & 63;
    const float4* bp = (const float4*)(basis + (size_t)j * 8);
    const int4*   ip = (const int4*)(idx + (size_t)j * 8);
    float4 b0 = bp[0], b1 = bp[1];
    int4   i0 = ip[0], i1 = ip[1];
    float bv[8] = {b0.x, b0.y, b0.z, b0.w, b1.x, b1.y, b1.z, b1.w};
    int   kv[8] = {i0.x, i0.y, i0.z, i0.w, i1.x, i1.y, i1.z, i1.w};
    float m = 0.0f;
#pragma unroll
    for (int s = 0; s < 8; ++s) m += bv[s] * W1[kv[s] * 64 + l];
    atomicAdd(&acc[(size_t)rowS[j] * 64 + l], m);
}

// h = (elu?)(acc/max(deg,1) + bias); optional fp32 and/or bf16 outputs
__global__ void finalize_kernel(const float* __restrict__ acc, const float* __restrict__ deg,
                                const float* __restrict__ bias, float* __restrict__ outF,
                                unsigned short* __restrict__ outB,
                                int N, int F, int do_elu) {
    int t = blockIdx.x * blockDim.x + threadIdx.x;
    if (t >= N * F) return;
    int n = t / F, o = t % F;
    float v = acc[t] / fmaxf(deg[n], 1.0f) + bias[o];
    if (do_elu) v = (v > 0.0f) ? v : (expf(v) - 1.0f);
    if (outF) outF[t] = v;
    if (outB) outB[t] = f2b(v);
}

__global__ void castbf_kernel(const float* __restrict__ in, unsigned short* __restrict__ out,
                              int n) {
    int t = blockIdx.x * blockDim.x + threadIdx.x;
    if (t < n) out[t] = f2b(in[t]);
}

// Pack W [Kc][Fin][Fout] (fp32) into MFMA B-fragment order (bf16).
__global__ void pack_w_kernel(const float* __restrict__ W, unsigned short* __restrict__ BF,
                              int Kc, int Fin, int Fout, int ksteps) {
    int t = blockIdx.x * blockDim.x + threadIdx.x;
    int total = Kc * Fout * Fin;
    if (t >= total) return;
    int c = t / Fin;
    int i = t % Fin;
    int kk = c / Fout, o = c % Fout;
    int ct = c >> 4, lr = c & 15;
    int step = i >> 5, rem = i & 31, lg = rem >> 3, jj = rem & 7;
    size_t dst = ((((size_t)ct * ksteps + step) * 4 + lg) * 16 + lr) * 8 + jj;
    BF[dst] = f2b(W[((size_t)kk * Fin + i) * Fout + o]);
}

// z = A @ B via mfma_f32_16x16x32_bf16. A [M][KSTEPS*32] bf16 row-major.
template<int KSTEPS, int OUT_BF16>
__global__ __launch_bounds__(256) void zgemm_kernel(
        const unsigned short* __restrict__ A, int M,
        const unsigned short* __restrict__ BF,
        void* __restrict__ Z, int zld, int ct0, int zct) {
    int w = threadIdx.x >> 6, l = threadIdx.x & 63;
    int m0 = blockIdx.x * 64 + w * 16;
    int lr = l & 15, lg = l >> 4;
    const int KD = KSTEPS * 32;
    f32x4 acc[4];
#pragma unroll
    for (int cf = 0; cf < 4; ++cf) acc[cf] = (f32x4){0.f, 0.f, 0.f, 0.f};
    int arow = m0 + lr; if (arow > M - 1) arow = M - 1;
#pragma unroll
    for (int step = 0; step < KSTEPS; ++step) {
        s16x8 a = *(const s16x8*)(A + (size_t)arow * KD + step * 32 + lg * 8);
#pragma unroll
        for (int cf = 0; cf < 4; ++cf) {
            int ctl = blockIdx.y * 4 + cf;
            if (ctl < zct) {
                int ctg = ct0 + ctl;
                const unsigned short* bp =
                    BF + ((((size_t)ctg * KSTEPS + step) * 4 + lg) * 16 + lr) * 8;
                s16x8 b = *(const s16x8*)bp;
                acc[cf] = __builtin_amdgcn_mfma_f32_16x16x32_bf16(a, b, acc[cf], 0, 0, 0);
            }
        }
    }
#pragma unroll
    for (int cf = 0; cf < 4; ++cf) {
        int ctl = blockIdx.y * 4 + cf;
        if (ctl >= zct) continue;
        int colc = ctl * 16 + lr;
#pragma unroll
        for (int r = 0; r < 4; ++r) {
            int rowc = m0 + lg * 4 + r;
            if (rowc < M) {
                if (OUT_BF16)
                    ((unsigned short*)Z)[(size_t)rowc * zld + colc] = f2b(acc[cf][r]);
                else
                    ((float*)Z)[(size_t)rowc * zld + colc] = acc[cf][r];
            }
        }
    }
}

// gather conv2: wave per sorted edge, lane = out channel (64). z bf16 [N][zld].
__global__ __launch_bounds__(256) void gather2_kernel(
        const unsigned short* __restrict__ z, int zld,
        const float* __restrict__ basis, const int* __restrict__ idx,
        const int* __restrict__ rowS, const int* __restrict__ colS,
        float* __restrict__ acc, int E, int k0, int k1) {
    int b = swzblk();
    int j = b * 4 + (threadIdx.x >> 6);
    if (j >= E) return;
    int l = threadIdx.x & 63;
    const float4* bp = (const float4*)(basis + (size_t)j * 8);
    const int4*   ip = (const int4*)(idx + (size_t)j * 8);
    float4 b0 = bp[0], b1 = bp[1];
    int4   i0 = ip[0], i1 = ip[1];
    float bv[8] = {b0.x, b0.y, b0.z, b0.w, b1.x, b1.y, b1.z, b1.w};
    int   kv[8] = {i0.x, i0.y, i0.z, i0.w, i1.x, i1.y, i1.z, i1.w};
    size_t zb = (size_t)colS[j] * zld;
    float m = 0.0f;
    bool any = false;
    unsigned short zv[8];
#pragma unroll
    for (int s = 0; s < 8; ++s) {
        int k = kv[s];
        zv[s] = (k >= k0 && k < k1) ? z[zb + (size_t)(k - k0) * 64 + l] : (unsigned short)0;
    }
#pragma unroll
    for (int s = 0; s < 8; ++s) {
        int k = kv[s];
        if (k >= k0 && k < k1) { m += bv[s] * b2f(zv[s]); any = true; }
    }
    if (any) atomicAdd(&acc[(size_t)rowS[j] * 64 + l], m);
}

// gather conv3: half-wave per sorted edge (32 out channels). z bf16 [N][zld].
__global__ __launch_bounds__(256) void gather3_kernel(
        const unsigned short* __restrict__ z, int zld,
        const float* __restrict__ basis, const int* __restrict__ idx,
        const int* __restrict__ rowS, const int* __restrict__ colS,
        float* __restrict__ acc, int E, int k0, int k1) {
    int b = swzblk();
    int j = b * 8 + (threadIdx.x >> 5);
    if (j >= E) return;
    int o = threadIdx.x & 31;
    const float4* bp = (const float4*)(basis + (size_t)j * 8);
    const int4*   ip = (const int4*)(idx + (size_t)j * 8);
    float4 b0 = bp[0], b1 = bp[1];
    int4   i0 = ip[0], i1 = ip[1];
    float bv[8] = {b0.x, b0.y, b0.z, b0.w, b1.x, b1.y, b1.z, b1.w};
    int   kv[8] = {i0.x, i0.y, i0.z, i0.w, i1.x, i1.y, i1.z, i1.w};
    size_t zb = (size_t)colS[j] * zld;
    float m = 0.0f;
    bool any = false;
    unsigned short zv[8];
#pragma unroll
    for (int s = 0; s < 8; ++s) {
        int k = kv[s];
        zv[s] = (k >= k0 && k < k1) ? z[zb + (size_t)(k - k0) * 32 + o] : (unsigned short)0;
    }
#pragma unroll
    for (int s = 0; s < 8; ++s) {
        int k = kv[s];
        if (k >= k0 && k < k1) { m += bv[s] * b2f(zv[s]); any = true; }
    }
    if (any) atomicAdd(&acc[(size_t)rowS[j] * 32 + o], m);
}

// stn3 + stn4 per node
__global__ __launch_bounds__(64) void stn34_kernel(
        const float* __restrict__ h2, const float* __restrict__ w3,
        const float* __restrict__ b3, const float* __restrict__ w4,
        const float* __restrict__ b4, float* __restrict__ t, int N) {
    int n = blockIdx.x;
    int o = threadIdx.x;
    __shared__ float sh[64];
    __shared__ float sh3[64];
    sh[o] = h2[n * 64 + o];
    __syncthreads();
    float v = b3[o];
#pragma unroll
    for (int i = 0; i < 64; ++i) v += sh[i] * w3[i * 64 + o];
    v = (v > 0.0f) ? v : (expf(v) - 1.0f);
    sh3[o] = v;
    __syncthreads();
    if (o < 3) {
        float tv = b4[o];
#pragma unroll
        for (int i = 0; i < 64; ++i) tv += sh3[i] * w4[i * 3 + o];
        t[n * 3 + o] = tv;
    }
}

// ---- fallback (R1) conv kernels, used only if ws too small ----
__global__ __launch_bounds__(256) void conv2f_kernel(
        const float* __restrict__ h1, const float* __restrict__ basis,
        const int* __restrict__ idx, const int* __restrict__ row,
        const int* __restrict__ col, const float* __restrict__ W2,
        float* __restrict__ acc, int E) {
    int wid = threadIdx.x >> 6;
    int lane = threadIdx.x & 63;
    int e = blockIdx.x * 4 + wid;
    __shared__ float sh[4][64];
    bool active = (e < E);
    int c = active ? col[e] : 0;
    if (active) sh[wid][lane] = h1[c * 64 + lane];
    __syncthreads();
    if (!active) return;
    float b[8]; int id[8];
#pragma unroll
    for (int s = 0; s < 8; ++s) { b[s] = basis[e * 8 + s]; id[s] = idx[e * 8 + s]; }
    float m = 0.0f;
#pragma unroll
    for (int s = 0; s < 8; ++s) {
        const float* Wk = W2 + (size_t)id[s] * 4096;
        float ms = 0.0f;
#pragma unroll
        for (int i = 0; i < 64; ++i) ms += sh[wid][i] * Wk[i * 64 + lane];
        m += b[s] * ms;
    }
    atomicAdd(&acc[row[e] * 64 + lane], m);
}

__global__ __launch_bounds__(256) void conv3f_kernel(
        const float* __restrict__ x, const float* __restrict__ basis,
        const int* __restrict__ idx, const int* __restrict__ row,
        const int* __restrict__ col, const float* __restrict__ Wc,
        float* __restrict__ acc, int E) {
    int wid = threadIdx.x >> 6;
    int lane = threadIdx.x & 63;
    int e = blockIdx.x * 4 + wid;
    __shared__ float sx[4][32];
    bool active = (e < E);
    int c = active ? col[e] : 0;
    if (active && lane < 32) sx[wid][lane] = x[c * 32 + lane];
    __syncthreads();
    int half = lane >> 5;
    int o = lane & 31;
    float m = 0.0f;
    if (active) {
#pragma unroll
        for (int s2 = 0; s2 < 4; ++s2) {
            int s = half * 4 + s2;
            float b = basis[e * 8 + s];
            const float* Wk = Wc + (size_t)idx[e * 8 + s] * 1024;
            float ms = 0.0f;
#pragma unroll
            for (int i = 0; i < 32; ++i) ms += sx[wid][i] * Wk[i * 32 + o];
            m += b * ms;
        }
    }
    m += __shfl_xor(m, 32);
    if (active && lane < 32) atomicAdd(&acc[row[e] * 32 + o], m);
}

extern "C" void kernel_launch(void* const* d_in, const int* in_sizes, int n_in,
                              void* d_out, int out_size, void* d_ws, size_t ws_size,
                              hipStream_t stream) {
    const float* x      = (const float*)d_in[0];
    const int*   ei     = (const int*)d_in[1];
    const float* pseudo = (const float*)d_in[2];
    const float* w1     = (const float*)d_in[3];
    const float* b1     = (const float*)d_in[4];
    const float* w2     = (const float*)d_in[5];
    const float* b2     = (const float*)d_in[6];
    const float* w3     = (const float*)d_in[7];
    const float* b3     = (const float*)d_in[8];
    const float* w4     = (const float*)d_in[9];
    const float* b4     = (const float*)d_in[10];
    const float* wc     = (const float*)d_in[11];
    const float* cb     = (const float*)d_in[12];
    float* out = (float*)d_out;

    const int N = in_sizes[0] / 32;
    const int E = in_sizes[1] / 2;
    const int* row = ei;
    const int* col = ei + E;
    const int KC = 125;

    char* p = (char*)d_ws;
    // zeroed region
    float* deg  = (float*)p; p += (size_t)N * sizeof(float);
    int*   hist = (int*)p;   p += (size_t)N * sizeof(int);
    float* acc1 = (float*)p; p += (size_t)N * 64 * sizeof(float);
    float* acc2 = (float*)p; p += (size_t)N * 64 * sizeof(float);
    float* acc3 = (float*)p; p += (size_t)N * 32 * sizeof(float);
    size_t zero_bytes = (size_t)(p - (char*)d_ws);
    // non-zeroed
    int*   cursor = (int*)p; p += (size_t)N * sizeof(int);
    int*   jpos   = (int*)p; p += (size_t)E * sizeof(int);
    int*   rowS   = (int*)p; p += (size_t)E * sizeof(int);
    int*   colS   = (int*)p; p += (size_t)E * sizeof(int);
    float* h2   = (float*)p; p += (size_t)N * 64 * sizeof(float);
    float* tt   = (float*)p; p += (size_t)N * 3 * sizeof(float);
    float* basis = (float*)p; p += (size_t)E * 8 * sizeof(float);
    int*   idx   = (int*)p;  p += (size_t)E * 8 * sizeof(int);
    unsigned short* h1b = (unsigned short*)p; p += (size_t)N * 64 * sizeof(short);
    unsigned short* xb  = (unsigned short*)p; p += (size_t)N * 32 * sizeof(short);
    unsigned short* BF2 = (unsigned short*)p; p += (size_t)KC * 64 * 64 * sizeof(short);
    unsigned short* BF3 = (unsigned short*)p; p += (size_t)KC * 32 * 32 * sizeof(short);
    float* h1f = (float*)p;  // overlaps z area; only used in fallback
    size_t fixed = (size_t)(p - (char*)d_ws);
    size_t zcap = (ws_size > fixed) ? (ws_size - fixed) : 0;

    const size_t z2_per_k = (size_t)N * 64 * sizeof(short);
    const size_t z3_per_k = (size_t)N * 32 * sizeof(short);
    int KC2 = (int)(zcap / z2_per_k); if (KC2 > KC) KC2 = KC;
    int KC3 = (int)(zcap / z3_per_k); if (KC3 > KC) KC3 = KC;
    bool fast2 = KC2 >= 1;
    bool fast3 = KC3 >= 1;
    bool sorted = fast2 && fast3;
    void* zbuf = (void*)p;

    hipMemsetAsync(d_ws, 0, zero_bytes, stream);

    if (fast2)
        pack_w_kernel<<<(KC * 64 * 64 + 255) / 256, 256, 0, stream>>>(w2, BF2, KC, 64, 64, 2);
    if (fast3) {
        pack_w_kernel<<<(KC * 32 * 32 + 255) / 256, 256, 0, stream>>>(wc, BF3, KC, 32, 32, 1);
        castbf_kernel<<<(N * 32 + 255) / 256, 256, 0, stream>>>(x, xb, N * 32);
    }

    histdeg_kernel<<<(E + 255) / 256, 256, 0, stream>>>(row, col, deg, hist, E);

    const int* rowG = row;  // row array for gather kernels
    const int* colG = col;
    const int* jp = nullptr;
    if (sorted) {
        scan_kernel<<<1, 1024, 0, stream>>>(hist, cursor, N);
        scatter_kernel<<<(E + 255) / 256, 256, 0, stream>>>(row, col, cursor, jpos, rowS, colS, E);
        rowG = rowS; colG = colS; jp = jpos;
    }

    basis1_kernel<<<(E + 255) / 256, 256, 0, stream>>>(pseudo, jp, basis, idx, E);
    conv1_kernel<<<(E + 3) / 4, 256, 0, stream>>>(basis, idx, rowG, w1, acc1, E);
    finalize_kernel<<<(N * 64 + 255) / 256, 256, 0, stream>>>(
        acc1, deg, b1, fast2 ? nullptr : h1f, fast2 ? h1b : nullptr, N, 64, 1);

    const int MT = (N + 63) / 64;

    // ---- conv2 ----
    if (fast2) {
        for (int k0 = 0; k0 < KC; k0 += KC2) {
            int kcur = KC - k0 < KC2 ? KC - k0 : KC2;
            int zld = kcur * 64;
            dim3 g(MT, kcur);
            zgemm_kernel<2, 1><<<g, 256, 0, stream>>>(h1b, N, BF2, zbuf, zld, k0 * 4, kcur * 4);
            gather2_kernel<<<(E + 3) / 4, 256, 0, stream>>>(
                (const unsigned short*)zbuf, zld, basis, idx, rowG, colG, acc2, E,
                k0, k0 + kcur);
        }
    } else {
        conv2f_kernel<<<(E + 3) / 4, 256, 0, stream>>>(h1f, basis, idx, row, col, w2, acc2, E);
    }
    finalize_kernel<<<(N * 64 + 255) / 256, 256, 0, stream>>>(acc2, deg, b2, h2, nullptr, N, 64, 1);

    stn34_kernel<<<N, 64, 0, stream>>>(h2, w3, b3, w4, b4, tt, N);
    basis2_kernel<<<(E + 255) / 256, 256, 0, stream>>>(pseudo, tt, row, col, jp, basis, idx, E);

    // ---- conv3 ----
    if (fast3) {
        for (int k0 = 0; k0 < KC; k0 += KC3) {
            int kcur = KC - k0 < KC3 ? KC - k0 : KC3;
            int zld = kcur * 32;
            dim3 g(MT, (kcur * 32 + 63) / 64);
            zgemm_kernel<1, 1><<<g, 256, 0, stream>>>(xb, N, BF3, zbuf, zld, k0 * 2, kcur * 2);
            gather3_kernel<<<(E + 7) / 8, 256, 0, stream>>>(
                (const unsigned short*)zbuf, zld, basis, idx, rowG, colG, acc3, E,
                k0, k0 + kcur);
        }
    } else {
        conv3f_kernel<<<(E + 3) / 4, 256, 0, stream>>>(x, basis, idx, row, col, wc, acc3, E);
    }
    finalize_kernel<<<(N * 32 + 255) / 256, 256, 0, stream>>>(acc3, deg, cb, out, nullptr, N, 32, 0);
}